// Round 1
// baseline (275.620 us; speedup 1.0000x reference)
//
#include <hip/hip_runtime.h>
#include <hip/hip_bf16.h>
#include <cstdint>

#define NPTS 8192
#define DIM  128
#define NA   1024
#define KSEL 64

// ---------------------------------------------------------------------------
// Kernel 1: L1 distance matrix, GEMM-style tiling.
//   Rows 0..1023    : a1[i] = out1[anchor1[i]]  vs  out2   (dir 0)
//   Rows 1024..2047 : a2[i] = out2[anchor2[i]]  vs  out1   (dir 1)
// Tile: BM=32 anchors x BN=128 candidates, K split in 2 chunks of 64 dims.
// Per thread: 4x4 accumulators. LDS chunk-XOR swizzle keeps all ds_read_b128
// at the linear-equivalent (best-case) bank pattern.
// ---------------------------------------------------------------------------
#define BM 32
#define BN 128
#define BKD 64

__global__ __launch_bounds__(256, 3)
void dist_kernel(const float* __restrict__ out1, const float* __restrict__ out2,
                 const int* __restrict__ anchor1, const int* __restrict__ anchor2,
                 float* __restrict__ Dmat) {
  // swizzled layout: element (row, d) lives at [row][ ((d>>2) ^ ((row>>2)&7))*4 + (d&3) ]
  __shared__ float At[BM][BKD];
  __shared__ float Bt[BN][BKD];
  __shared__ int anch[BM];

  const int t  = threadIdx.x;
  const int mt = blockIdx.x & 63;   // 64 M-tiles (32 per direction)
  const int nt = blockIdx.x >> 6;   // 64 N-tiles
  const int dir = mt >> 5;
  const int i0  = (mt & 31) * BM;
  const int j0  = nt * BN;

  const float* __restrict__ Abase = dir ? out2 : out1;
  const float* __restrict__ Bbase = dir ? out1 : out2;
  const int* __restrict__ anc     = dir ? anchor2 : anchor1;

  if (t < BM) anch[t] = anc[i0 + t];

  const int ty = t >> 5;   // 0..7
  const int tx = t & 31;   // 0..31

  float acc[4][4];
#pragma unroll
  for (int r = 0; r < 4; ++r)
#pragma unroll
    for (int c = 0; c < 4; ++c) acc[r][c] = 0.f;

  for (int kk = 0; kk < DIM; kk += BKD) {
    __syncthreads();  // first iter: after anchor load; later: protect LDS reuse
    // stage A: 32 rows x 64 floats = 512 float4 chunks, 2 per thread
#pragma unroll
    for (int q = 0; q < 2; ++q) {
      int idx = t * 2 + q;            // 0..511
      int r   = idx >> 4;             // 0..31
      int kc  = idx & 15;             // chunk within row
      float4 v = *(const float4*)(Abase + (size_t)anch[r] * DIM + kk + kc * 4);
      int col = ((kc ^ ((r >> 2) & 7)) << 2);
      *(float4*)(&At[r][col]) = v;
    }
    // stage B: 128 rows x 64 floats = 2048 float4 chunks, 8 per thread
#pragma unroll
    for (int q = 0; q < 8; ++q) {
      int idx = t + q * 256;          // 0..2047
      int r   = idx >> 4;             // 0..127
      int kc  = idx & 15;
      float4 v = *(const float4*)(Bbase + (size_t)(j0 + r) * DIM + kk + kc * 4);
      int col = ((kc ^ ((r >> 2) & 7)) << 2);
      *(float4*)(&Bt[r][col]) = v;
    }
    __syncthreads();

#pragma unroll
    for (int kc = 0; kc < 16; ++kc) {
      float4 av[4], bv[4];
#pragma unroll
      for (int r = 0; r < 4; ++r)
        av[r] = *(const float4*)(&At[ty * 4 + r][(kc ^ ty) << 2]);
#pragma unroll
      for (int c = 0; c < 4; ++c)
        bv[c] = *(const float4*)(&Bt[tx * 4 + c][(kc ^ (tx & 7)) << 2]);
#pragma unroll
      for (int r = 0; r < 4; ++r)
#pragma unroll
        for (int c = 0; c < 4; ++c) {
          acc[r][c] += fabsf(av[r].x - bv[c].x);
          acc[r][c] += fabsf(av[r].y - bv[c].y);
          acc[r][c] += fabsf(av[r].z - bv[c].z);
          acc[r][c] += fabsf(av[r].w - bv[c].w);
        }
    }
  }

#pragma unroll
  for (int r = 0; r < 4; ++r) {
    float4 v = make_float4(acc[r][0], acc[r][1], acc[r][2], acc[r][3]);
    size_t row = (size_t)(dir * NA + i0 + ty * 4 + r);
    *(float4*)(Dmat + row * NPTS + j0 + tx * 4) = v;
  }
}

// ---------------------------------------------------------------------------
// Kernel 2: per (dir, anchor): exact top-64 selection (binary search on the
// uint32 key of the f32 distance — monotone for non-negative floats, no
// atomic-histogram contention), then hinge-loss terms on the selected set.
// ---------------------------------------------------------------------------
__global__ __launch_bounds__(256, 4)
void select_loss_kernel(const float* __restrict__ out1, const float* __restrict__ out2,
                        const float* __restrict__ ot,
                        const int* __restrict__ anchor1, const int* __restrict__ anchor2,
                        const float* __restrict__ Dmat, float* __restrict__ partials) {
  __shared__ float sd[NPTS];       // 32 KiB distance row
  __shared__ float a_self[DIM];
  __shared__ float terms[KSEL];
  __shared__ int   sel[KSEL];
  __shared__ unsigned wred[4];
  __shared__ float sm_pos;
  __shared__ int sm_cnt, sm_tie;

  const int t   = threadIdx.x;
  const int b   = blockIdx.x;
  const int dir = b >> 10;
  const int i   = b & (NA - 1);

  const int a1i = anchor1[i];
  const int a2i = anchor2[i];
  const int ai_self = dir ? a2i : a1i;
  const float* __restrict__ selfB = dir ? out2 : out1;
  const float* __restrict__ othB  = dir ? out1 : out2;

  // load distance row
  const float4* drow = (const float4*)(Dmat + (size_t)b * NPTS);
#pragma unroll
  for (int q = 0; q < 8; ++q) ((float4*)sd)[t + q * 256] = drow[t + q * 256];

  if (t < 32) ((float4*)a_self)[t] = ((const float4*)(selfB + (size_t)ai_self * DIM))[t];

  if (t == 0) { sm_cnt = 0; sm_tie = 0; }

  // pos = sum |a1 - a2|  (same for both directions), wave 0
  if (t < 64) {
    const float* r1 = out1 + (size_t)a1i * DIM;
    const float* r2 = out2 + (size_t)a2i * DIM;
    float p = fabsf(r1[t] - r2[t]) + fabsf(r1[t + 64] - r2[t + 64]);
#pragma unroll
    for (int o = 32; o; o >>= 1) p += __shfl_down(p, o);
    if (t == 0) sm_pos = p;
  }
  __syncthreads();

  // cache this thread's 32 keys
  unsigned keys[32];
#pragma unroll
  for (int q = 0; q < 32; ++q) keys[q] = __float_as_uint(sd[t + q * 256]);

  // binary search: smallest u with count(keys <= u) >= 64  ->  u = 64th smallest
  unsigned lo = 0u, hi = 0x7F800000u;
  while (lo < hi) {
    unsigned mid = lo + ((hi - lo) >> 1);
    unsigned c = 0;
#pragma unroll
    for (int q = 0; q < 32; ++q) c += (keys[q] <= mid) ? 1u : 0u;
#pragma unroll
    for (int o = 32; o; o >>= 1) c += __shfl_down(c, o);
    if ((t & 63) == 0) wred[t >> 6] = c;
    __syncthreads();
    c = wred[0] + wred[1] + wred[2] + wred[3];
    if (c >= 64u) hi = mid; else lo = mid + 1u;
    __syncthreads();  // protect wred reuse
  }
  const unsigned T = lo;

  // nLess = count(keys < T)
  {
    unsigned c = 0;
#pragma unroll
    for (int q = 0; q < 32; ++q) c += (keys[q] < T) ? 1u : 0u;
#pragma unroll
    for (int o = 32; o; o >>= 1) c += __shfl_down(c, o);
    if ((t & 63) == 0) wred[t >> 6] = c;
  }
  __syncthreads();
  const int need = 64 - (int)(wred[0] + wred[1] + wred[2] + wred[3]);

  // collect exactly 64 indices
#pragma unroll
  for (int q = 0; q < 32; ++q) {
    unsigned k = keys[q];
    bool take = false;
    if (k < T) take = true;
    else if (k == T) take = (atomicAdd(&sm_tie, 1) < need);
    if (take) {
      int s = atomicAdd(&sm_cnt, 1);
      sel[s] = t + q * 256;
    }
  }
  __syncthreads();

  // loss terms: 4 threads per selected negative (32 dims each)
  {
    const int s  = t >> 2;
    const int tq = t & 3;
    const int j  = sel[s];
    const float w = dir ? ot[(size_t)j * NPTS + ai_self]
                        : ot[(size_t)ai_self * NPTS + j];
    const float* br = othB + (size_t)j * DIM;
    float dist = 0.f;
#pragma unroll
    for (int d = 0; d < 32; d += 4) {
      float4 bv = *(const float4*)(br + tq * 32 + d);
      dist += fabsf(a_self[tq * 32 + d + 0] - w * bv.x);
      dist += fabsf(a_self[tq * 32 + d + 1] - w * bv.y);
      dist += fabsf(a_self[tq * 32 + d + 2] - w * bv.z);
      dist += fabsf(a_self[tq * 32 + d + 3] - w * bv.w);
    }
    dist += __shfl_xor(dist, 1);
    dist += __shfl_xor(dist, 2);
    if (tq == 0) terms[s] = fmaxf(0.f, sm_pos + 1.0f - dist);
  }
  __syncthreads();

  if (t < 64) {
    float v = terms[t];
#pragma unroll
    for (int o = 32; o; o >>= 1) v += __shfl_down(v, o);
    if (t == 0) partials[b] = v;
  }
}

// ---------------------------------------------------------------------------
// Kernel 3: deterministic reduction of 2048 partials, scale by 1/(A*K).
// ---------------------------------------------------------------------------
__global__ __launch_bounds__(256)
void reduce_kernel(const float* __restrict__ partials, float* __restrict__ outp) {
  __shared__ float ws4[4];
  const int t = threadIdx.x;
  float v = 0.f;
#pragma unroll
  for (int q = 0; q < 8; ++q) v += partials[t + q * 256];
#pragma unroll
  for (int o = 32; o; o >>= 1) v += __shfl_down(v, o);
  if ((t & 63) == 0) ws4[t >> 6] = v;
  __syncthreads();
  if (t == 0) outp[0] = (ws4[0] + ws4[1] + ws4[2] + ws4[3]) * (1.0f / 65536.0f);
}

extern "C" void kernel_launch(void* const* d_in, const int* in_sizes, int n_in,
                              void* d_out, int out_size, void* d_ws, size_t ws_size,
                              hipStream_t stream) {
  (void)in_sizes; (void)n_in; (void)out_size; (void)ws_size;
  const float* out1  = (const float*)d_in[0];
  const float* out2  = (const float*)d_in[1];
  const float* ot    = (const float*)d_in[2];
  const int* anchor1 = (const int*)d_in[3];
  const int* anchor2 = (const int*)d_in[4];

  // ws layout: D matrix [2048][8192] f32 (64 MiB) + 2048 partials
  float* Dmat     = (float*)d_ws;
  float* partials = Dmat + (size_t)2 * NA * NPTS;

  dist_kernel<<<dim3(64 * 64), dim3(256), 0, stream>>>(out1, out2, anchor1, anchor2, Dmat);
  select_loss_kernel<<<dim3(2 * NA), dim3(256), 0, stream>>>(out1, out2, ot, anchor1, anchor2,
                                                             Dmat, partials);
  reduce_kernel<<<dim3(1), dim3(256), 0, stream>>>(partials, (float*)d_out);
}